// Round 20
// baseline (211.632 us; speedup 1.0000x reference)
//
#include <hip/hip_runtime.h>
#include <math.h>

#define NTOK   262144
#define DIM    64
#define NCODE  1024
#define LOSSOFF (NTOK*DIM)          // 16777216
#define IDXOFF  (NTOK*DIM + 1)

// Margin covers: ref's fp32 quantization reorder (2*ulp(D~64..128) ~ 3.05e-5
// worst tail) + MFMA-split dd error (<= ~3e-7). 4e-5 holds with headroom;
// 2e-5 would NOT (tail tokens with |x|^2 ~ 128). Flag rate ~1.7%.
#define MARGIN 4e-5f
#define RCAP   65536

// ws float-offsets
#define OFF_BC     0               // 1024 f
#define OFF_CBHI   1024            // ushort[65536] = 32768 f
#define OFF_CBMID  33792           // 32768 f
#define OFF_RCNT   66560           // 1 int
#define OFF_CORR   66561           // 1 float
#define OFF_RLIST  66562           // 65536 int
#define OFF_BLK    132098          // 2048 f
#define WS_FLOATS  134146

typedef __attribute__((ext_vector_type(8))) short short8;
typedef __attribute__((ext_vector_type(16))) float f32x16;

__device__ __forceinline__ ushort bf16rn(float f) {
    unsigned u = __float_as_uint(f);
    return (ushort)((u + 0x7fffu + ((u >> 16) & 1u)) >> 16);
}
__device__ __forceinline__ float bf16tof(ushort h) {
    return __uint_as_float(((unsigned)h) << 16);
}

__global__ __launch_bounds__(256) void vq_prep_cb(const float* __restrict__ cb,
                                                  float* __restrict__ ws) {
    int c = blockIdx.x * 256 + threadIdx.x;
    if (c == 0) { ((int*)ws)[OFF_RCNT] = 0; ws[OFF_CORR] = 0.f; }
    if (c >= NCODE) return;
    ushort* cbh = (ushort*)(ws + OFF_CBHI);
    ushort* cbm = (ushort*)(ws + OFF_CBMID);
    const float4* p = (const float4*)(cb + (size_t)c * DIM);
    float a0 = 0.f, a1 = 0.f, a2 = 0.f, a3 = 0.f;
#pragma unroll
    for (int i = 0; i < 16; i++) {
        float4 v = p[i];
        a0 = fmaf(v.x, v.x, a0); a1 = fmaf(v.y, v.y, a1);
        a2 = fmaf(v.z, v.z, a2); a3 = fmaf(v.w, v.w, a3);
        ushort4 h, m;
        h.x = bf16rn(v.x); m.x = bf16rn(v.x - bf16tof(h.x));
        h.y = bf16rn(v.y); m.y = bf16rn(v.y - bf16tof(h.y));
        h.z = bf16rn(v.z); m.z = bf16rn(v.z - bf16tof(h.z));
        h.w = bf16rn(v.w); m.w = bf16rn(v.w - bf16tof(h.w));
        ((ushort4*)(cbh + (size_t)c * 64))[i] = h;
        ((ushort4*)(cbm + (size_t)c * 64))[i] = m;
    }
    ws[OFF_BC + c] = (a0 + a1) + (a2 + a3);   // exact R2 prep chain
}

// 32x32x16 MFMA distance pass: 12 MFMAs per 32 codes x 32 tokens (was 24 of
// 16x16x32) -> -17% matrix-pipe cycles, half the issue slots. Same staging
// bytes, same ping-pong single-barrier rounds (16), same zero-conflict
// aliasing structure. Layouts: C col=lane&31,row=(reg&3)+8*(reg>>2)+4*(l>>5)
// [HW-verified m74/m101]; A row=lane&31 / B col=lane&31, k=(l>>5)*8+j.
__global__ __launch_bounds__(256)
__attribute__((amdgpu_waves_per_eu(3)))
void vq_mfma(const float* __restrict__ x,
             const float* __restrict__ cbf,
             float* __restrict__ out,
             float* __restrict__ ws) {
    __shared__ uint4 smem[2][1024];   // 32KB: [set][tile(2)*512 + code*16 + part*8 + g']
    __shared__ int idxs[128];
    __shared__ float red[4];
    const float* Bc = ws + OFF_BC;
    const ushort* cbh = (const ushort*)(ws + OFF_CBHI);
    const ushort* cbm = (const ushort*)(ws + OFF_CBMID);

    int tid = threadIdx.x, lane = tid & 63, wv = tid >> 6;
    int col = lane & 31, h = lane >> 5;
    int tokb = blockIdx.x * 128 + wv * 32;
    int token = tokb + col;

    // X (B-operand) fragments: lane holds x[token=col][k = kc*16 + h*8 + j]
    short8 Xhi[4], Xmid[4];
    {
        const float* xr = x + (size_t)token * 64;
#pragma unroll
        for (int kc = 0; kc < 4; ++kc) {
            float4 v0 = *(const float4*)(xr + kc * 16 + h * 8);
            float4 v1 = *(const float4*)(xr + kc * 16 + h * 8 + 4);
            float vv[8] = {v0.x, v0.y, v0.z, v0.w, v1.x, v1.y, v1.z, v1.w};
            short8 hv, mv;
#pragma unroll
            for (int j = 0; j < 8; ++j) {
                ushort hb = bf16rn(vv[j]);
                float r = vv[j] - bf16tof(hb);   // exact (Sterbenz)
                hv[j] = (short)hb; mv[j] = (short)bf16rn(r);
            }
            Xhi[kc] = hv; Xmid[kc] = mv;
        }
    }

    // per-slot trackers: slot rr covers code c0 + (rr&3) + 8*(rr>>2) + 4*h
    float best[16], sec[16];
    int bbase[16];
#pragma unroll
    for (int rr = 0; rr < 16; ++rr) {
        best[rr] = 3.4e38f; sec[rr] = 3.4e38f; bbase[rr] = 0;
    }

    // staging descriptors: 4 granules/thread/round (2 tiles x 2 parts x 32
    // codes x 8 granules = 1024 x 16B per round)
    const ushort* gsrc[4];
    int gdst[4];
#pragma unroll
    for (int it = 0; it < 4; ++it) {
        int gi = it * 256 + tid;
        int tile = gi >> 9, part = (gi >> 8) & 1, code = (gi >> 3) & 31, g = gi & 7;
        gsrc[it] = (part ? cbm : cbh) + (size_t)(tile * 32 + code) * 64 + g * 8;
        gdst[it] = tile * 512 + code * 16 + part * 8 + (g ^ (code & 7));
    }
    // A-fragment read offsets (hi at part 0, mid at part 8; +8 outside xor)
    int ro_h[4];
#pragma unroll
    for (int kc = 0; kc < 4; ++kc)
        ro_h[kc] = col * 16 + ((kc * 2 + h) ^ (col & 7));

    // prefill: round 0 -> set 0; issue round-1 loads
    uint4 r0 = *(const uint4*)(gsrc[0]);
    uint4 r1 = *(const uint4*)(gsrc[1]);
    uint4 r2 = *(const uint4*)(gsrc[2]);
    uint4 r3 = *(const uint4*)(gsrc[3]);
    smem[0][gdst[0]] = r0; smem[0][gdst[1]] = r1;
    smem[0][gdst[2]] = r2; smem[0][gdst[3]] = r3;
    r0 = *(const uint4*)(gsrc[0] + 4096);
    r1 = *(const uint4*)(gsrc[1] + 4096);
    r2 = *(const uint4*)(gsrc[2] + 4096);
    r3 = *(const uint4*)(gsrc[3] + 4096);
    __syncthreads();

    for (int rd = 0; rd < 16; ++rd) {
        int set = rd & 1;
        if (rd < 15) {
            int ns = set ^ 1;
            smem[ns][gdst[0]] = r0; smem[ns][gdst[1]] = r1;
            smem[ns][gdst[2]] = r2; smem[ns][gdst[3]] = r3;
            if (rd < 14) {   // loads for round rd+2: vmcnt slack = 1 full round
                size_t off = (size_t)(rd + 2) * 4096;
                r0 = *(const uint4*)(gsrc[0] + off);
                r1 = *(const uint4*)(gsrc[1] + off);
                r2 = *(const uint4*)(gsrc[2] + off);
                r3 = *(const uint4*)(gsrc[3] + off);
            }
        }
#pragma unroll
        for (int sub = 0; sub < 2; ++sub) {
            int c0 = (rd * 2 + sub) * 32;
            const uint4* tb = &smem[set][sub * 512];
            short8 Ah0 = __builtin_bit_cast(short8, tb[ro_h[0]]);
            short8 Ah1 = __builtin_bit_cast(short8, tb[ro_h[1]]);
            short8 Ah2 = __builtin_bit_cast(short8, tb[ro_h[2]]);
            short8 Ah3 = __builtin_bit_cast(short8, tb[ro_h[3]]);
            short8 Am0 = __builtin_bit_cast(short8, tb[ro_h[0] + 8]);
            short8 Am1 = __builtin_bit_cast(short8, tb[ro_h[1] + 8]);
            short8 Am2 = __builtin_bit_cast(short8, tb[ro_h[2] + 8]);
            short8 Am3 = __builtin_bit_cast(short8, tb[ro_h[3] + 8]);
            float4 bq0 = *(const float4*)(Bc + c0 + 0 * 8 + h * 4);
            float4 bq1 = *(const float4*)(Bc + c0 + 1 * 8 + h * 4);
            float4 bq2 = *(const float4*)(Bc + c0 + 2 * 8 + h * 4);
            float4 bq3 = *(const float4*)(Bc + c0 + 3 * 8 + h * 4);
            float bqa[16] = {bq0.x, bq0.y, bq0.z, bq0.w,
                             bq1.x, bq1.y, bq1.z, bq1.w,
                             bq2.x, bq2.y, bq2.z, bq2.w,
                             bq3.x, bq3.y, bq3.z, bq3.w};
            f32x16 acc = {0.f};
            acc = __builtin_amdgcn_mfma_f32_32x32x16_bf16(Ah0, Xhi[0], acc, 0, 0, 0);
            acc = __builtin_amdgcn_mfma_f32_32x32x16_bf16(Ah1, Xhi[1], acc, 0, 0, 0);
            acc = __builtin_amdgcn_mfma_f32_32x32x16_bf16(Ah2, Xhi[2], acc, 0, 0, 0);
            acc = __builtin_amdgcn_mfma_f32_32x32x16_bf16(Ah3, Xhi[3], acc, 0, 0, 0);
            acc = __builtin_amdgcn_mfma_f32_32x32x16_bf16(Ah0, Xmid[0], acc, 0, 0, 0);
            acc = __builtin_amdgcn_mfma_f32_32x32x16_bf16(Ah1, Xmid[1], acc, 0, 0, 0);
            acc = __builtin_amdgcn_mfma_f32_32x32x16_bf16(Ah2, Xmid[2], acc, 0, 0, 0);
            acc = __builtin_amdgcn_mfma_f32_32x32x16_bf16(Ah3, Xmid[3], acc, 0, 0, 0);
            acc = __builtin_amdgcn_mfma_f32_32x32x16_bf16(Am0, Xhi[0], acc, 0, 0, 0);
            acc = __builtin_amdgcn_mfma_f32_32x32x16_bf16(Am1, Xhi[1], acc, 0, 0, 0);
            acc = __builtin_amdgcn_mfma_f32_32x32x16_bf16(Am2, Xhi[2], acc, 0, 0, 0);
            acc = __builtin_amdgcn_mfma_f32_32x32x16_bf16(Am3, Xhi[3], acc, 0, 0, 0);
#pragma unroll
            for (int rr = 0; rr < 16; ++rr) {
                float d = fmaf(-2.f, acc[rr], bqa[rr]);
                bool lt = d < best[rr];
                sec[rr] = __builtin_amdgcn_fmed3f(d, best[rr], sec[rr]);
                best[rr] = fminf(best[rr], d);
                bbase[rr] = lt ? c0 : bbase[rr];
            }
        }
        __syncthreads();   // single barrier per round
    }

    // merge 16 slots in-lane (explicit index tie-break: exact first-min)
    {
        float b = best[0], s2 = sec[0];
        int bi = bbase[0] + 4 * h;
#pragma unroll
        for (int rr = 1; rr < 16; ++rr) {
            float ob = best[rr];
            int oi = bbase[rr] + (rr & 3) + 8 * (rr >> 2) + 4 * h;
            s2 = fminf(fminf(s2, sec[rr]), fmaxf(b, ob));
            bool lt = (ob < b) || (ob == b && oi < bi);
            b = lt ? ob : b; bi = lt ? oi : bi;
        }
        // cross-lane: partner lane (xor 32) holds same token, rows +-4
        float ob = __shfl_xor(b, 32, 64);
        float os = __shfl_xor(s2, 32, 64);
        int   oi = __shfl_xor(bi, 32, 64);
        s2 = fminf(fminf(s2, os), fmaxf(b, ob));
        bool lt = (ob < b) || (ob == b && oi < bi);
        b = lt ? ob : b; bi = lt ? oi : bi;
        if (lane < 32) {
            out[IDXOFF + token] = (float)bi;
            idxs[wv * 32 + lane] = bi;
            if (s2 - b < MARGIN) {
                int pos = atomicAdd((int*)ws + OFF_RCNT, 1);
                if (pos < RCAP) ((int*)ws)[OFF_RLIST + pos] = token;
            }
        }
    }
    __syncthreads();

    // fused quantized + loss epilogue (refine later corrects flagged rows)
    float se = 0.f;
    int tokb0 = blockIdx.x * 128;
#pragma unroll
    for (int i = 0; i < 8; ++i) {
        int gi = i * 256 + tid;
        int tok = gi >> 4, qd = gi & 15;
        int ci = idxs[tok];
        float4 xvv = *(const float4*)(x + (size_t)(tokb0 + tok) * 64 + qd * 4);
        float4 qv = *(const float4*)(cbf + (size_t)ci * 64 + qd * 4);
        float d0 = qv.x - xvv.x, d1 = qv.y - xvv.y;
        float d2 = qv.z - xvv.z, d3 = qv.w - xvv.w;
        float4 o;
        o.x = xvv.x + d0; o.y = xvv.y + d1; o.z = xvv.z + d2; o.w = xvv.w + d3;
        *(float4*)(out + (size_t)(tokb0 + tok) * 64 + qd * 4) = o;
        se += d0 * d0 + d1 * d1 + d2 * d2 + d3 * d3;
    }
    for (int off = 32; off; off >>= 1) se += __shfl_down(se, off, 64);
    if (lane == 0) red[wv] = se;
    __syncthreads();
    if (tid == 0) ws[OFF_BLK + blockIdx.x] = (red[0] + red[1]) + (red[2] + red[3]);
}

// exact fp32 re-scan for flagged tokens; fixes quantized rows + loss delta.
__global__ __launch_bounds__(256) void vq_refine(const float* __restrict__ x,
                                                 const float* __restrict__ cb,
                                                 float* __restrict__ out,
                                                 float* __restrict__ ws) {
    __shared__ float ctile[128][64];               // 32KB
    __shared__ float xs[8][64];
    __shared__ float As[8];
    __shared__ int   tokid[8], oidx[8], nidx[8];
    __shared__ unsigned long long rkeys[8][128];   // 8KB
    __shared__ float dred[4];

    int cnt = min(((int*)ws)[OFF_RCNT], RCAP);
    if (cnt <= 0) return;
    int ngroups = (cnt + 7) >> 3;
    int tid = threadIdx.x;
    int code = tid & 127, th = tid >> 7;

    for (int grp = blockIdx.x; grp < ngroups; grp += gridDim.x) {
        if (tid < 8) {
            int i = grp * 8 + tid;
            int t = ((int*)ws)[OFF_RLIST + min(i, cnt - 1)];
            tokid[tid] = t;
            oidx[tid] = (int)out[IDXOFF + t];
        }
        __syncthreads();
#pragma unroll
        for (int it = 0; it < 2; ++it) {
            int idx = it * 256 + tid;
            xs[idx >> 6][idx & 63] = x[(size_t)tokid[idx >> 6] * 64 + (idx & 63)];
        }
        __syncthreads();
        if (tid < 8) {   // exact R2 A-chain
            float a0 = 0.f, a1 = 0.f, a2 = 0.f, a3 = 0.f;
#pragma unroll
            for (int kc = 0; kc < 16; ++kc) {
                float4 xk = *(const float4*)(xs[tid] + kc * 4);
                a0 = fmaf(xk.x, xk.x, a0); a1 = fmaf(xk.y, xk.y, a1);
                a2 = fmaf(xk.z, xk.z, a2); a3 = fmaf(xk.w, xk.w, a3);
            }
            As[tid] = (a0 + a1) + (a2 + a3);
        }

        unsigned long long bk[4] = {~0ull, ~0ull, ~0ull, ~0ull};
        int tb = th * 4;

        for (int pass = 0; pass < 8; ++pass) {
            int cbase = pass * 128;
            __syncthreads();
#pragma unroll
            for (int it = 0; it < 8; ++it) {
                int gi = it * 256 + tid;
                int cc = gi >> 4, qq = gi & 15;
                float4 v = *(const float4*)(cb + (size_t)(cbase + cc) * 64 + qq * 4);
                *(float4*)&ctile[cc][(qq ^ (cc & 15)) * 4] = v;
            }
            __syncthreads();

            float p0 = 0.f, p1 = 0.f, p2 = 0.f, p3 = 0.f;
#pragma unroll
            for (int qq = 0; qq < 16; ++qq) {
                float4 cv = *(const float4*)&ctile[code][(qq ^ (code & 15)) * 4];
                float4 x0 = *(const float4*)(xs[tb + 0] + qq * 4);
                float4 x1 = *(const float4*)(xs[tb + 1] + qq * 4);
                float4 x2 = *(const float4*)(xs[tb + 2] + qq * 4);
                float4 x3 = *(const float4*)(xs[tb + 3] + qq * 4);
                p0 = fmaf(x0.x, cv.x, p0); p0 = fmaf(x0.y, cv.y, p0);
                p0 = fmaf(x0.z, cv.z, p0); p0 = fmaf(x0.w, cv.w, p0);
                p1 = fmaf(x1.x, cv.x, p1); p1 = fmaf(x1.y, cv.y, p1);
                p1 = fmaf(x1.z, cv.z, p1); p1 = fmaf(x1.w, cv.w, p1);
                p2 = fmaf(x2.x, cv.x, p2); p2 = fmaf(x2.y, cv.y, p2);
                p2 = fmaf(x2.z, cv.z, p2); p2 = fmaf(x2.w, cv.w, p2);
                p3 = fmaf(x3.x, cv.x, p3); p3 = fmaf(x3.y, cv.y, p3);
                p3 = fmaf(x3.z, cv.z, p3); p3 = fmaf(x3.w, cv.w, p3);
            }
            float bn = ws[OFF_BC + cbase + code];
            int gcode = cbase + code;
            float pv[4] = {p0, p1, p2, p3};
#pragma unroll
            for (int j = 0; j < 4; ++j) {
                float s = As[tb + j] + bn;
                float d = fmaf(-2.0f, pv[j], s);   // == fl(s - 2p)
                unsigned long long key =
                    (((unsigned long long)__float_as_uint(d)) << 32) | (unsigned)gcode;
                bk[j] = min(bk[j], key);
            }
        }
        __syncthreads();
#pragma unroll
        for (int j = 0; j < 4; ++j) rkeys[tb + j][code] = bk[j];
        __syncthreads();

        int wv2 = tid >> 6, lane = tid & 63;
#pragma unroll
        for (int u = 0; u < 2; ++u) {
            int tt = wv2 * 2 + u;
            unsigned long long k = min(rkeys[tt][lane], rkeys[tt][lane + 64]);
#pragma unroll
            for (int off = 32; off; off >>= 1)
                k = min(k, (unsigned long long)__shfl_xor((long long)k, off, 64));
            if (lane == 0) {
                int ni = (int)(unsigned)(k & 0xffffffffull);
                nidx[tt] = ni;
                if (grp * 8 + tt < cnt) out[IDXOFF + tokid[tt]] = (float)ni;
            }
        }
        __syncthreads();

        float delta = 0.f;
        {
            int tok = tid >> 5, e2 = (tid & 31) * 2;
            if (grp * 8 + tok < cnt) {
                int nw = nidx[tok], od = oidx[tok];
                if (nw != od) {
                    float x0 = xs[tok][e2], x1 = xs[tok][e2 + 1];
                    float qn0 = cb[(size_t)nw * 64 + e2], qn1 = cb[(size_t)nw * 64 + e2 + 1];
                    float qo0 = cb[(size_t)od * 64 + e2], qo1 = cb[(size_t)od * 64 + e2 + 1];
                    float dn0 = qn0 - x0, dn1 = qn1 - x1;
                    float do0 = qo0 - x0, do1 = qo1 - x1;
                    out[(size_t)tokid[tok] * 64 + e2]     = x0 + dn0;
                    out[(size_t)tokid[tok] * 64 + e2 + 1] = x1 + dn1;
                    delta = (dn0 * dn0 + dn1 * dn1) - (do0 * do0 + do1 * do1);
                }
            }
        }
        for (int off = 32; off; off >>= 1) delta += __shfl_down(delta, off, 64);
        if ((tid & 63) == 0) dred[tid >> 6] = delta;
        __syncthreads();
        if (tid == 0) {
            float dsum = (dred[0] + dred[1]) + (dred[2] + dred[3]);
            if (dsum != 0.f) atomicAdd(ws + OFF_CORR, dsum);
        }
        __syncthreads();
    }
}

__global__ __launch_bounds__(256) void vq_loss2(float* __restrict__ out,
                                                const float* __restrict__ ws) {
    const float* blk = ws + OFF_BLK;
    __shared__ double sd[256];
    double s = 0.0;
    for (int i = threadIdx.x; i < 2048; i += 256) s += (double)blk[i];
    sd[threadIdx.x] = s;
    __syncthreads();
    for (int off = 128; off; off >>= 1) {
        if (threadIdx.x < off) sd[threadIdx.x] += sd[threadIdx.x + off];
        __syncthreads();
    }
    if (threadIdx.x == 0) {
        double tot = sd[0] + (double)ws[OFF_CORR];
        out[LOSSOFF] = (float)(1.25 * tot / ((double)NTOK * (double)DIM));
    }
}

extern "C" void kernel_launch(void* const* d_in, const int* in_sizes, int n_in,
                              void* d_out, int out_size, void* d_ws, size_t ws_size,
                              hipStream_t stream) {
    (void)in_sizes; (void)n_in; (void)out_size; (void)ws_size;
    const float* x = (const float*)d_in[0];
    const float* cb = (const float*)d_in[1];
    float* out = (float*)d_out;
    float* ws = (float*)d_ws;

    hipLaunchKernelGGL(vq_prep_cb, dim3(4), dim3(256), 0, stream, cb, ws);
    hipLaunchKernelGGL(vq_mfma, dim3(2048), dim3(256), 0, stream, x, cb, out, ws);
    hipLaunchKernelGGL(vq_refine, dim3(1024), dim3(256), 0, stream, x, cb, out, ws);
    hipLaunchKernelGGL(vq_loss2, dim3(1), dim3(256), 0, stream, out, ws);
}

// Round 21
// 156.004 us; speedup vs baseline: 1.3566x; 1.3566x over previous
//
#include <hip/hip_runtime.h>
#include <math.h>

#define NTOK   262144
#define DIM    64
#define NCODE  1024
#define LOSSOFF (NTOK*DIM)          // 16777216
#define IDXOFF  (NTOK*DIM + 1)

// Margin covers: ref's fp32 quantization reorder (2*ulp(D~64..128) ~ 3.05e-5
// worst tail) + MFMA-split dd error (<= ~3e-7). 4e-5 holds with headroom.
#define MARGIN 4e-5f
#define RCAP   65536

// ws float-offsets
#define OFF_BC     0               // 1024 f
#define OFF_CBHI   1024            // ushort[65536] = 32768 f (SWIZZLED rows)
#define OFF_CBMID  33792           // 32768 f (SWIZZLED rows)
#define OFF_RCNT   66560           // 1 int
#define OFF_CORR   66561           // 1 float
#define OFF_RLIST  66562           // 65536 int
#define OFF_BLK    132098          // 2048 f
#define WS_FLOATS  134146

typedef __attribute__((ext_vector_type(8))) short short8;
typedef __attribute__((ext_vector_type(4))) float f32x4;

// async global->LDS, 16B/lane, dest = wave-uniform base + lane*16 (linear)
#define GLOAD_LDS(g, l) __builtin_amdgcn_global_load_lds(                    \
    (const __attribute__((address_space(1))) void*)(g),                     \
    (__attribute__((address_space(3))) void*)(l), 16, 0, 0)

__device__ __forceinline__ ushort bf16rn(float f) {
    unsigned u = __float_as_uint(f);
    return (ushort)((u + 0x7fffu + ((u >> 16) & 1u)) >> 16);
}
__device__ __forceinline__ float bf16tof(ushort h) {
    return __uint_as_float(((unsigned)h) << 16);
}

// prep: splits codebook into bf16 hi/mid; rows stored PRE-SWIZZLED
// (ushort4 slot i holds original chunk i^((c&7)<<1)) so that a LINEAR
// global_load_lds copy reproduces the champion's swizzled LDS layout
// (rule 21: inverse-swz source + linear dest + swz read).
__global__ __launch_bounds__(256) void vq_prep_cb(const float* __restrict__ cb,
                                                  float* __restrict__ ws) {
    int c = blockIdx.x * 256 + threadIdx.x;
    if (c == 0) { ((int*)ws)[OFF_RCNT] = 0; ws[OFF_CORR] = 0.f; }
    if (c >= NCODE) return;
    ushort* cbh = (ushort*)(ws + OFF_CBHI);
    ushort* cbm = (ushort*)(ws + OFF_CBMID);
    const float4* p = (const float4*)(cb + (size_t)c * DIM);
    int sw = (c & 7) << 1;   // xor on ushort4 index (preserves 8B half-pairs)
    float a0 = 0.f, a1 = 0.f, a2 = 0.f, a3 = 0.f;
#pragma unroll
    for (int i = 0; i < 16; i++) {
        float4 v = p[i];
        a0 = fmaf(v.x, v.x, a0); a1 = fmaf(v.y, v.y, a1);
        a2 = fmaf(v.z, v.z, a2); a3 = fmaf(v.w, v.w, a3);
        ushort4 h, m;
        h.x = bf16rn(v.x); m.x = bf16rn(v.x - bf16tof(h.x));
        h.y = bf16rn(v.y); m.y = bf16rn(v.y - bf16tof(h.y));
        h.z = bf16rn(v.z); m.z = bf16rn(v.z - bf16tof(h.z));
        h.w = bf16rn(v.w); m.w = bf16rn(v.w - bf16tof(h.w));
        ((ushort4*)(cbh + (size_t)c * 64))[i ^ sw] = h;
        ((ushort4*)(cbm + (size_t)c * 64))[i ^ sw] = m;
    }
    ws[OFF_BC + c] = (a0 + a1) + (a2 + a3);   // exact R2 prep chain
}

// R18 champion structure; staging via global_load_lds (no VGPR round-trip,
// no ds_write instructions). Wave w stages a linear 1KB slice per tile:
// waves 0-1 = hi codes 0-7/8-15, waves 2-3 = mid. LDS image byte-identical
// to the champion -> ds_reads and distances bit-identical.
__global__ __launch_bounds__(256)
__attribute__((amdgpu_waves_per_eu(3)))
void vq_mfma(const float* __restrict__ x,
             const float* __restrict__ cbf,
             float* __restrict__ out,
             float* __restrict__ ws) {
    __shared__ uint4 smem[8][256];   // 32KB: two 4-tile sets
    __shared__ int idxs[128];
    __shared__ float red[4];
    const float* Bc = ws + OFF_BC;
    const ushort* cbh = (const ushort*)(ws + OFF_CBHI);
    const ushort* cbm = (const ushort*)(ws + OFF_CBMID);

    int tid = threadIdx.x, lane = tid & 63, wv = tid >> 6;
    int col = lane & 15, q = lane >> 4, q4 = q * 4;
    int tokb = blockIdx.x * 128 + wv * 32;

    short8 Xhi[2][2], Xmid[2][2];
#pragma unroll
    for (int tt = 0; tt < 2; ++tt) {
        int token = tokb + tt * 16 + col;
        const float* xr = x + (size_t)token * 64;
#pragma unroll
        for (int s = 0; s < 2; ++s) {
            float4 v0 = *(const float4*)(xr + s * 32 + q * 8);
            float4 v1 = *(const float4*)(xr + s * 32 + q * 8 + 4);
            float vv[8] = {v0.x, v0.y, v0.z, v0.w, v1.x, v1.y, v1.z, v1.w};
            short8 hv, mv;
#pragma unroll
            for (int j = 0; j < 8; ++j) {
                ushort h = bf16rn(vv[j]);
                float r = vv[j] - bf16tof(h);   // exact (Sterbenz)
                hv[j] = (short)h; mv[j] = (short)bf16rn(r);
            }
            Xhi[tt][s] = hv; Xmid[tt][s] = mv;
        }
    }

    float best[2][4], sec[2][4];
    int bbase[2][4];
#pragma unroll
    for (int tt = 0; tt < 2; ++tt)
#pragma unroll
        for (int rr = 0; rr < 4; ++rr) {
            best[tt][rr] = 3.4e38f; sec[tt][rr] = 3.4e38f; bbase[tt][rr] = 0;
        }

    // wave's staging source: 1KB linear per tile (pre-swizzled rows)
    const ushort* wsrc = (wv < 2 ? cbh : cbm) + (size_t)(wv & 1) * 512 + lane * 8;
    // ds_read offsets (champion's swizzled reads, unchanged)
    int ro_h0 = col * 8 + ((0 + q) ^ (col & 7));
    int ro_h1 = col * 8 + ((4 + q) ^ (col & 7));
    int ro_m0 = 128 + col * 8 + ((0 + q) ^ (col & 7));
    int ro_m1 = 128 + col * 8 + ((4 + q) ^ (col & 7));

    // prologue: tiles 0..3 -> bufs 0..3 (async; barrier drains vmcnt)
#pragma unroll
    for (int t = 0; t < 4; ++t)
        GLOAD_LDS(wsrc + t * 1024, &smem[t][wv * 64]);
    __syncthreads();

    for (int rd = 0; rd < 16; ++rd) {
        int base = (rd & 1) << 2;    // set being read
        if (rd < 15) {               // issue next round's tiles into other set
            int nb = 4 - base;
            const ushort* ts = wsrc + (size_t)(rd + 1) * 4096;
#pragma unroll
            for (int t = 0; t < 4; ++t)
                GLOAD_LDS(ts + t * 1024, &smem[nb + t][wv * 64]);
        }
#pragma unroll
        for (int sub = 0; sub < 4; ++sub) {
            int c0 = (rd * 4 + sub) * 16;
            float4 bq = *(const float4*)(Bc + c0 + q4);
            short8 Ah0 = *(const short8*)&smem[base + sub][ro_h0];
            short8 Ah1 = *(const short8*)&smem[base + sub][ro_h1];
            short8 Am0 = *(const short8*)&smem[base + sub][ro_m0];
            short8 Am1 = *(const short8*)&smem[base + sub][ro_m1];
            int bv = c0 + q4;
            float bqv[4] = {bq.x, bq.y, bq.z, bq.w};
#pragma unroll
            for (int tt = 0; tt < 2; ++tt) {
                f32x4 acc = {0.f, 0.f, 0.f, 0.f};
                acc = __builtin_amdgcn_mfma_f32_16x16x32_bf16(Ah0, Xhi[tt][0], acc, 0, 0, 0);
                acc = __builtin_amdgcn_mfma_f32_16x16x32_bf16(Ah1, Xhi[tt][1], acc, 0, 0, 0);
                acc = __builtin_amdgcn_mfma_f32_16x16x32_bf16(Ah0, Xmid[tt][0], acc, 0, 0, 0);
                acc = __builtin_amdgcn_mfma_f32_16x16x32_bf16(Ah1, Xmid[tt][1], acc, 0, 0, 0);
                acc = __builtin_amdgcn_mfma_f32_16x16x32_bf16(Am0, Xhi[tt][0], acc, 0, 0, 0);
                acc = __builtin_amdgcn_mfma_f32_16x16x32_bf16(Am1, Xhi[tt][1], acc, 0, 0, 0);
#pragma unroll
                for (int rr = 0; rr < 4; ++rr) {
                    float d = fmaf(-2.f, acc[rr], bqv[rr]);
                    bool lt = d < best[tt][rr];
                    sec[tt][rr] = __builtin_amdgcn_fmed3f(d, best[tt][rr], sec[tt][rr]);
                    best[tt][rr] = fminf(best[tt][rr], d);
                    bbase[tt][rr] = lt ? bv : bbase[tt][rr];
                }
            }
        }
        __syncthreads();   // single barrier per round (drains async loads)
    }

#pragma unroll
    for (int tt = 0; tt < 2; ++tt) {
        float b = best[tt][0], s2 = sec[tt][0];
        int bi = bbase[tt][0];
#pragma unroll
        for (int rr = 1; rr < 4; ++rr) {
            float ob = best[tt][rr];
            int oi = bbase[tt][rr] + rr;
            s2 = fminf(fminf(s2, sec[tt][rr]), fmaxf(b, ob));
            bool lt2 = (ob < b) || (ob == b && oi < bi);
            b = lt2 ? ob : b; bi = lt2 ? oi : bi;
        }
#pragma unroll
        for (int off = 16; off <= 32; off <<= 1) {
            float ob = __shfl_xor(b, off, 64);
            float os = __shfl_xor(s2, off, 64);
            int   oi = __shfl_xor(bi, off, 64);
            s2 = fminf(fminf(s2, os), fmaxf(b, ob));
            bool lt = (ob < b) || (ob == b && oi < bi);
            b = lt ? ob : b; bi = lt ? oi : bi;
        }
        if (lane < 16) {
            int token = tokb + tt * 16 + lane;
            out[IDXOFF + token] = (float)bi;
            idxs[wv * 32 + tt * 16 + lane] = bi;
            if (s2 - b < MARGIN) {
                int pos = atomicAdd((int*)ws + OFF_RCNT, 1);
                if (pos < RCAP) ((int*)ws)[OFF_RLIST + pos] = token;
            }
        }
    }
    __syncthreads();

    // fused quantized + loss epilogue (refine later corrects flagged rows)
    float se = 0.f;
    int tokb0 = blockIdx.x * 128;
#pragma unroll
    for (int i = 0; i < 8; ++i) {
        int gi = i * 256 + tid;
        int tok = gi >> 4, qd = gi & 15;
        int ci = idxs[tok];
        float4 xvv = *(const float4*)(x + (size_t)(tokb0 + tok) * 64 + qd * 4);
        float4 qv = *(const float4*)(cbf + (size_t)ci * 64 + qd * 4);
        float d0 = qv.x - xvv.x, d1 = qv.y - xvv.y;
        float d2 = qv.z - xvv.z, d3 = qv.w - xvv.w;
        float4 o;
        o.x = xvv.x + d0; o.y = xvv.y + d1; o.z = xvv.z + d2; o.w = xvv.w + d3;
        *(float4*)(out + (size_t)(tokb0 + tok) * 64 + qd * 4) = o;
        se += d0 * d0 + d1 * d1 + d2 * d2 + d3 * d3;
    }
    for (int off = 32; off; off >>= 1) se += __shfl_down(se, off, 64);
    if (lane == 0) red[wv] = se;
    __syncthreads();
    if (tid == 0) ws[OFF_BLK + blockIdx.x] = (red[0] + red[1]) + (red[2] + red[3]);
}

// exact fp32 re-scan for flagged tokens; fixes quantized rows + loss delta.
__global__ __launch_bounds__(256) void vq_refine(const float* __restrict__ x,
                                                 const float* __restrict__ cb,
                                                 float* __restrict__ out,
                                                 float* __restrict__ ws) {
    __shared__ float ctile[128][64];               // 32KB
    __shared__ float xs[8][64];
    __shared__ float As[8];
    __shared__ int   tokid[8], oidx[8], nidx[8];
    __shared__ unsigned long long rkeys[8][128];   // 8KB
    __shared__ float dred[4];

    int cnt = min(((int*)ws)[OFF_RCNT], RCAP);
    if (cnt <= 0) return;
    int ngroups = (cnt + 7) >> 3;
    int tid = threadIdx.x;
    int code = tid & 127, th = tid >> 7;

    for (int grp = blockIdx.x; grp < ngroups; grp += gridDim.x) {
        if (tid < 8) {
            int i = grp * 8 + tid;
            int t = ((int*)ws)[OFF_RLIST + min(i, cnt - 1)];
            tokid[tid] = t;
            oidx[tid] = (int)out[IDXOFF + t];
        }
        __syncthreads();
#pragma unroll
        for (int it = 0; it < 2; ++it) {
            int idx = it * 256 + tid;
            xs[idx >> 6][idx & 63] = x[(size_t)tokid[idx >> 6] * 64 + (idx & 63)];
        }
        __syncthreads();
        if (tid < 8) {   // exact R2 A-chain
            float a0 = 0.f, a1 = 0.f, a2 = 0.f, a3 = 0.f;
#pragma unroll
            for (int kc = 0; kc < 16; ++kc) {
                float4 xk = *(const float4*)(xs[tid] + kc * 4);
                a0 = fmaf(xk.x, xk.x, a0); a1 = fmaf(xk.y, xk.y, a1);
                a2 = fmaf(xk.z, xk.z, a2); a3 = fmaf(xk.w, xk.w, a3);
            }
            As[tid] = (a0 + a1) + (a2 + a3);
        }

        unsigned long long bk[4] = {~0ull, ~0ull, ~0ull, ~0ull};
        int tb = th * 4;

        for (int pass = 0; pass < 8; ++pass) {
            int cbase = pass * 128;
            __syncthreads();
#pragma unroll
            for (int it = 0; it < 8; ++it) {
                int gi = it * 256 + tid;
                int cc = gi >> 4, qq = gi & 15;
                float4 v = *(const float4*)(cb + (size_t)(cbase + cc) * 64 + qq * 4);
                *(float4*)&ctile[cc][(qq ^ (cc & 15)) * 4] = v;
            }
            __syncthreads();

            float p0 = 0.f, p1 = 0.f, p2 = 0.f, p3 = 0.f;
#pragma unroll
            for (int qq = 0; qq < 16; ++qq) {
                float4 cv = *(const float4*)&ctile[code][(qq ^ (code & 15)) * 4];
                float4 x0 = *(const float4*)(xs[tb + 0] + qq * 4);
                float4 x1 = *(const float4*)(xs[tb + 1] + qq * 4);
                float4 x2 = *(const float4*)(xs[tb + 2] + qq * 4);
                float4 x3 = *(const float4*)(xs[tb + 3] + qq * 4);
                p0 = fmaf(x0.x, cv.x, p0); p0 = fmaf(x0.y, cv.y, p0);
                p0 = fmaf(x0.z, cv.z, p0); p0 = fmaf(x0.w, cv.w, p0);
                p1 = fmaf(x1.x, cv.x, p1); p1 = fmaf(x1.y, cv.y, p1);
                p1 = fmaf(x1.z, cv.z, p1); p1 = fmaf(x1.w, cv.w, p1);
                p2 = fmaf(x2.x, cv.x, p2); p2 = fmaf(x2.y, cv.y, p2);
                p2 = fmaf(x2.z, cv.z, p2); p2 = fmaf(x2.w, cv.w, p2);
                p3 = fmaf(x3.x, cv.x, p3); p3 = fmaf(x3.y, cv.y, p3);
                p3 = fmaf(x3.z, cv.z, p3); p3 = fmaf(x3.w, cv.w, p3);
            }
            float bn = ws[OFF_BC + cbase + code];
            int gcode = cbase + code;
            float pv[4] = {p0, p1, p2, p3};
#pragma unroll
            for (int j = 0; j < 4; ++j) {
                float s = As[tb + j] + bn;
                float d = fmaf(-2.0f, pv[j], s);   // == fl(s - 2p)
                unsigned long long key =
                    (((unsigned long long)__float_as_uint(d)) << 32) | (unsigned)gcode;
                bk[j] = min(bk[j], key);
            }
        }
        __syncthreads();
#pragma unroll
        for (int j = 0; j < 4; ++j) rkeys[tb + j][code] = bk[j];
        __syncthreads();

        int wv2 = tid >> 6, lane = tid & 63;
#pragma unroll
        for (int u = 0; u < 2; ++u) {
            int tt = wv2 * 2 + u;
            unsigned long long k = min(rkeys[tt][lane], rkeys[tt][lane + 64]);
#pragma unroll
            for (int off = 32; off; off >>= 1)
                k = min(k, (unsigned long long)__shfl_xor((long long)k, off, 64));
            if (lane == 0) {
                int ni = (int)(unsigned)(k & 0xffffffffull);
                nidx[tt] = ni;
                if (grp * 8 + tt < cnt) out[IDXOFF + tokid[tt]] = (float)ni;
            }
        }
        __syncthreads();

        float delta = 0.f;
        {
            int tok = tid >> 5, e2 = (tid & 31) * 2;
            if (grp * 8 + tok < cnt) {
                int nw = nidx[tok], od = oidx[tok];
                if (nw != od) {
                    float x0 = xs[tok][e2], x1 = xs[tok][e2 + 1];
                    float qn0 = cb[(size_t)nw * 64 + e2], qn1 = cb[(size_t)nw * 64 + e2 + 1];
                    float qo0 = cb[(size_t)od * 64 + e2], qo1 = cb[(size_t)od * 64 + e2 + 1];
                    float dn0 = qn0 - x0, dn1 = qn1 - x1;
                    float do0 = qo0 - x0, do1 = qo1 - x1;
                    out[(size_t)tokid[tok] * 64 + e2]     = x0 + dn0;
                    out[(size_t)tokid[tok] * 64 + e2 + 1] = x1 + dn1;
                    delta = (dn0 * dn0 + dn1 * dn1) - (do0 * do0 + do1 * do1);
                }
            }
        }
        for (int off = 32; off; off >>= 1) delta += __shfl_down(delta, off, 64);
        if ((tid & 63) == 0) dred[tid >> 6] = delta;
        __syncthreads();
        if (tid == 0) {
            float dsum = (dred[0] + dred[1]) + (dred[2] + dred[3]);
            if (dsum != 0.f) atomicAdd(ws + OFF_CORR, dsum);
        }
        __syncthreads();
    }
}

__global__ __launch_bounds__(256) void vq_loss2(float* __restrict__ out,
                                                const float* __restrict__ ws) {
    const float* blk = ws + OFF_BLK;
    __shared__ double sd[256];
    double s = 0.0;
    for (int i = threadIdx.x; i < 2048; i += 256) s += (double)blk[i];
    sd[threadIdx.x] = s;
    __syncthreads();
    for (int off = 128; off; off >>= 1) {
        if (threadIdx.x < off) sd[threadIdx.x] += sd[threadIdx.x + off];
        __syncthreads();
    }
    if (threadIdx.x == 0) {
        double tot = sd[0] + (double)ws[OFF_CORR];
        out[LOSSOFF] = (float)(1.25 * tot / ((double)NTOK * (double)DIM));
    }
}

extern "C" void kernel_launch(void* const* d_in, const int* in_sizes, int n_in,
                              void* d_out, int out_size, void* d_ws, size_t ws_size,
                              hipStream_t stream) {
    (void)in_sizes; (void)n_in; (void)out_size; (void)ws_size;
    const float* x = (const float*)d_in[0];
    const float* cb = (const float*)d_in[1];
    float* out = (float*)d_out;
    float* ws = (float*)d_ws;

    hipLaunchKernelGGL(vq_prep_cb, dim3(4), dim3(256), 0, stream, cb, ws);
    hipLaunchKernelGGL(vq_mfma, dim3(2048), dim3(256), 0, stream, x, cb, out, ws);
    hipLaunchKernelGGL(vq_refine, dim3(1024), dim3(256), 0, stream, x, cb, out, ws);
    hipLaunchKernelGGL(vq_loss2, dim3(1), dim3(256), 0, stream, out, ws);
}